// Round 1
// 277.694 us; speedup vs baseline: 1.0102x; 1.0102x over previous
//
#include <hip/hip_runtime.h>

// Problem constants (from reference)
#define BB 4
#define PP 12000
#define CC 64
#define HH 512
#define WW 512

// Kernel 1: winner[b*H*W + y*W + x] = max p among pillars hitting that cell.
// Winner buffer pre-initialized to -1 (0xFF memset). Max-p == last-write-wins
// in p order, matching XLA scatter-set semantics with duplicate indices.
__global__ void __launch_bounds__(256) winner_scatter(
    const int* __restrict__ coords, int* __restrict__ winner) {
    int tid = blockIdx.x * blockDim.x + threadIdx.x;
    if (tid >= BB * PP) return;
    int4 c4 = ((const int4*)coords)[tid];  // (batch, y, x, z)
    int y = c4.y;
    int x = c4.z;
    if (x >= 0 && x < WW && y >= 0 && y < HH) {
        int b = tid / PP;
        int p = tid - b * PP;
        atomicMax(&winner[(b * HH + y) * WW + x], p);
    }
}

// Kernel 2: output-linear fill. Thread i owns the float4 at linear offset i of
// out[B,C,H,W] -> stores form ONE sequential stream (memset-like, ~6.2 TB/s).
// Each thread: 1 coalesced int4 winner read (L2-resident: 1 MB footprint per
// c-plane sweep, re-read 64x), <=4 predicated gather loads from the 12 MB
// feature table (LLC-resident), 1 nontemporal float4 store (don't let the
// 268 MB dead-on-write output evict winner/features from L2).
typedef float f4_ev __attribute__((ext_vector_type(4)));

__global__ void __launch_bounds__(256) fill_linear(
    const float* __restrict__ feat, const int4* __restrict__ winner4,
    float4* __restrict__ out4) {
    int tid = blockIdx.x * blockDim.x + threadIdx.x;  // 0 .. B*C*H*W/4 = 2^24
    // linear out index = ((b*CC + c)*HH + y)*(WW/4) + x4
    int x4 = tid & (WW / 4 - 1);          // 7 bits
    int y  = (tid >> 7) & (HH - 1);       // 9 bits
    int c  = (tid >> 16) & (CC - 1);      // 6 bits
    int b  = tid >> 22;                   // 2 bits

    int4 w4 = winner4[(b * HH + y) * (WW / 4) + x4];

    const float* fbase = feat + (size_t)b * (PP * CC) + c;
    float4 v;
    v.x = (w4.x >= 0) ? fbase[(size_t)w4.x * CC] : 0.0f;
    v.y = (w4.y >= 0) ? fbase[(size_t)w4.y * CC] : 0.0f;
    v.z = (w4.z >= 0) ? fbase[(size_t)w4.z * CC] : 0.0f;
    v.w = (w4.w >= 0) ? fbase[(size_t)w4.w * CC] : 0.0f;

    __builtin_nontemporal_store(*(const f4_ev*)&v, (f4_ev*)&out4[tid]);
}

extern "C" void kernel_launch(void* const* d_in, const int* in_sizes, int n_in,
                              void* d_out, int out_size, void* d_ws, size_t ws_size,
                              hipStream_t stream) {
    const float* feat   = (const float*)d_in[0];  // [B, P, C] fp32
    const int*   coords = (const int*)d_in[1];    // [B, P, 4] int32
    float* out = (float*)d_out;                   // [B, C, H, W] fp32
    int* winner = (int*)d_ws;                     // [B, H, W] int32 (4 MB)

    // Init winner map to -1 (0xFF bytes). d_ws is poisoned each call, so this
    // must run every launch. Graph-capture-safe (memset node).
    hipMemsetAsync(winner, 0xFF, (size_t)BB * HH * WW * sizeof(int), stream);

    // Resolve duplicates: winner = max pillar index per cell.
    {
        int n = BB * PP;
        winner_scatter<<<(n + 255) / 256, 256, 0, stream>>>(coords, winner);
    }

    // Output-linear fill: zeros + gathered features, one sequential store stream.
    {
        int n = BB * CC * HH * WW / 4;  // 16,777,216 float4s
        fill_linear<<<n / 256, 256, 0, stream>>>(
            feat, (const int4*)winner, (float4*)out);
    }
}